// Round 9
// baseline (221.174 us; speedup 1.0000x reference)
//
#include <hip/hip_runtime.h>
#include <hip/hip_bf16.h>

// ---------------- problem constants ----------------
#define NIMG 16
#define CIN 128
#define COUT 256
#define HH 64
#define WW 64
#define KHE 7
#define KW_ 3
#define HP (HH + 6)   // 70
#define WP (WW + 2)   // 66
#define KDIM (CIN * KHE * KW_)  // 2688
#define NKT 42                  // K-tiles of 64

typedef __attribute__((ext_vector_type(8))) short short8;
typedef __attribute__((ext_vector_type(4))) float f32x4;

#define AS1(p) ((const __attribute__((address_space(1))) void*)(p))
#define AS3(p) ((__attribute__((address_space(3))) void*)(p))

// ---------------- kernel 1: pad + NCHW->NHWC transpose + f32->bf16 ----------------
__global__ void __launch_bounds__(256) pad_convert(const float* __restrict__ x,
                                                   ushort* __restrict__ xp) {
  const int bid = blockIdx.x;          // 16*70
  const int n = bid / HP, hp = bid % HP;
  const int h = hp - 3;
  ushort* dst = xp + (size_t)(n * HP + hp) * (WP * CIN);
  const int tid = threadIdx.x;

  if (h < 0 || h >= HH) {
    uint4* p = (uint4*)dst;
    uint4 z; z.x = z.y = z.z = z.w = 0u;
    for (int idx = tid; idx < (WP * CIN * 2) / 16; idx += 256) p[idx] = z;
    return;
  }

  __shared__ ushort t[CIN][WW + 1];
  for (int it = 0; it < (CIN * WW) / 256; ++it) {
    int flat = it * 256 + tid;
    int i = flat >> 6, w = flat & 63;
    float v = x[(((size_t)n * CIN + i) * HH + h) * WW + w];
    __hip_bfloat16 b = __float2bfloat16(v);
    t[i][w] = *(ushort*)&b;
  }
  __syncthreads();
  for (int it = 0; it < (WP * CIN) / 256; ++it) {
    int flat = it * 256 + tid;
    int wp = flat >> 7, i = flat & 127;
    int w = wp - 1;
    ushort v = (w < 0 || w >= WW) ? (ushort)0 : t[i][w];
    dst[flat] = v;
  }
}

// ---------------- kernel 2: build dense bf16 kernel in MFMA-fragment order ----------------
// kb2[kslice][o][32] where kslice = (kh_eff*3+kw)*4 + (i>>5), within-slice = i&31.
__global__ void __launch_bounds__(256) build_kb(const float* __restrict__ weight,
                                                const float* __restrict__ P,
                                                ushort* __restrict__ kb2) {
  int idx = blockIdx.x * 256 + threadIdx.x;
  if (idx >= COUT * KW_ * CIN) return;
  int i = idx & 127;
  int kw = (idx >> 7) % 3;
  int o = idx / (KW_ * CIN);
  int base = (o * CIN + i) * 9 + kw;

  float a[KHE] = {0.f, 0.f, 0.f, 0.f, 0.f, 0.f, 0.f};
#pragma unroll
  for (int kh = 0; kh < 3; ++kh) {
    float wv = weight[base + kh * 3];
    float p = P[base + kh * 3];
    p = fminf(2.f, fmaxf(-2.f, p));
    float pos = (float)(kh + 2) + p;
    float fl = floorf(pos);
    float fr = pos - fl;
    int r0 = (int)fl;
    float c0 = wv * (1.f - fr);
    float c1 = wv * fr;
#pragma unroll
    for (int r = 0; r < KHE; ++r) {
      a[r] += ((r0 == r) ? c0 : 0.f) + ((r0 + 1 == r) ? c1 : 0.f);
    }
  }
#pragma unroll
  for (int r = 0; r < KHE; ++r) {
    __hip_bfloat16 b = __float2bfloat16(a[r]);
    int kslice = (r * 3 + kw) * 4 + (i >> 5);
    kb2[(size_t)kslice * 8192 + o * 32 + (i & 31)] = *(ushort*)&b;
  }
}

// ---------------- kernel 3: implicit-GEMM conv, 128x128 tile, 4 waves, 3 blocks/CU ----------------
// M = 65536 (512 tiles), N = 256 (2 tiles), K = 2688 = 42 x 64
// 4 waves (2M x 2N), per-wave output 64x64 (acc = 16 f32x4 -> AGPRs).
// A via 3-buffer LDS (48 KiB), B via L2->regs double-buffered. 2 barriers/tile,
// counted vmcnt(12). TLP from 3 independent blocks/CU (launch_bounds(256,3)).
__global__ void __launch_bounds__(256, 3) dcls_gemm(const ushort* __restrict__ xp,
                                                    const ushort* __restrict__ kb2,
                                                    const float* __restrict__ bias,
                                                    float* __restrict__ out) {
  __shared__ __align__(16) ushort As[3][128 * 64];   // 48 KiB

  const int tid = threadIdx.x;
  const int lane = tid & 63;
  const int wv = tid >> 6;       // 0..3
  const int wr = wv >> 1;        // 0..1 along M
  const int wc = wv & 1;         // 0..1 along N
  const int g = lane >> 4;
  const int lm = lane & 15;

  // XCD-aware swizzle (nwg=1024, 8 XCDs, 128 blocks/XCD): each XCD gets a
  // contiguous logical chunk -> same N-half + contiguous M rows share its L2.
  const int bid = blockIdx.x;
  const int lid = (bid & 7) * 128 + (bid >> 3);
  const int mt = lid & 511;
  const int nt = lid >> 9;
  const int m0 = mt << 7;

  // A staging: 256 threads x 16B = 4KB per instr = 32 rows; source pre-swizzled (rule #21)
  const int swz = ((tid & 7) ^ ((tid >> 3) & 7)) * 8;

  const ushort* pA[4];
#pragma unroll
  for (int j = 0; j < 4; ++j) {
    int r = j * 32 + (tid >> 3);
    int m = m0 + r;
    int ni = m >> 12, hh = (m >> 6) & 63, ww = m & 63;
    pA[j] = xp + (size_t)((ni * HP + hh) * WP + ww) * CIN + swz;
  }

  // B fragment base: ((kslice*256 + o)*32 + g*8), o = nt*128 + wc*64 + nf*16 + lm
  const ushort* kbB = kb2 + (size_t)nt * 4096 + (size_t)wc * 2048 + lm * 32 + g * 8;

#define STAGEA(buf, kt) do { \
    int kh_ = (kt) / 6; int rem_ = (kt) - kh_ * 6; \
    int kw2_ = rem_ >> 1; int ic_ = rem_ & 1; \
    int offA_ = (kh_ * WP + kw2_) * CIN + ic_ * 64; \
    _Pragma("unroll") \
    for (int j_ = 0; j_ < 4; ++j_) \
      __builtin_amdgcn_global_load_lds(AS1(pA[j_] + offA_), \
          AS3(&As[buf][(j_ * 32 + wv * 8) * 64]), 16, 0, 0); \
  } while (0)

#define LOADB(dst, kt) do { \
    _Pragma("unroll") \
    for (int n_ = 0; n_ < 4; ++n_) \
      _Pragma("unroll") \
      for (int kk_ = 0; kk_ < 2; ++kk_) \
        dst[n_][kk_] = *(const short8*)(kbB + (size_t)((kt) * 2 + kk_) * 8192 + n_ * 512); \
  } while (0)

  f32x4 acc[4][4] = {};
  const int swzR = (lm & 7) << 4;

  short8 bf0[4][2], bf1[4][2];
  short8 af[4];

  // one kk half: 4 ds_read_b128 -> wait -> 16 MFMA
#define HALF(Ab, bfc, kk) do { \
    _Pragma("unroll") \
    for (int m4_ = 0; m4_ < 4; ++m4_) { \
      int rowA_ = wr * 64 + m4_ * 16 + lm; \
      af[m4_] = *(const short8*)((Ab) + rowA_ * 128 + (((kk) * 64 + g * 16) ^ swzR)); \
    } \
    __builtin_amdgcn_sched_barrier(0); \
    asm volatile("s_waitcnt lgkmcnt(0)" ::: "memory"); \
    __builtin_amdgcn_sched_barrier(0); \
    __builtin_amdgcn_s_setprio(1); \
    _Pragma("unroll") \
    for (int m4_ = 0; m4_ < 4; ++m4_) \
      _Pragma("unroll") \
      for (int n_ = 0; n_ < 4; ++n_) \
        acc[m4_][n_] = __builtin_amdgcn_mfma_f32_16x16x32_bf16( \
            af[m4_], bfc[n_][kk], acc[m4_][n_], 0, 0, 0); \
    __builtin_amdgcn_s_setprio(0); \
  } while (0)

  // one K-tile: vmcnt gate + data-ready barrier; compute; reads-done barrier; stage+prefetch
#define SUBITER(kt, bfc) do { \
    __builtin_amdgcn_sched_barrier(0); \
    asm volatile("s_waitcnt vmcnt(12)" ::: "memory"); \
    __builtin_amdgcn_s_barrier(); \
    __builtin_amdgcn_sched_barrier(0); \
    const char* Ab = (const char*)&As[(kt) % 3][0]; \
    HALF(Ab, bfc, 0); \
    HALF(Ab, bfc, 1); \
    __builtin_amdgcn_sched_barrier(0); \
    __builtin_amdgcn_s_barrier(); \
    __builtin_amdgcn_sched_barrier(0); \
    int ktn_ = ((kt) + 2 < NKT) ? (kt) + 2 : 0; \
    STAGEA(((kt) + 2) % 3, ktn_); \
    LOADB(bfc, ktn_); \
  } while (0)

  // prologue: A0,B0,A1,B1 -> 24 outstanding
  STAGEA(0, 0);
  LOADB(bf0, 0);
  STAGEA(1, 1);
  LOADB(bf1, 1);

  for (int kt = 0; kt < NKT; kt += 2) {
    SUBITER(kt, bf0);
    SUBITER(kt + 1, bf1);
  }
#undef SUBITER
#undef HALF
#undef LOADB
#undef STAGEA

  // keep tail prefetches alive (vmcnt-count integrity under unroll+DCE)
#pragma unroll
  for (int n_ = 0; n_ < 4; ++n_)
#pragma unroll
    for (int kk_ = 0; kk_ < 2; ++kk_) {
      asm volatile("" :: "v"((int)bf0[n_][kk_][0]));
      asm volatile("" :: "v"((int)bf1[n_][kk_][0]));
    }

  // epilogue: C/D layout col(o)=lane&15, row(m)=(lane>>4)*4+reg; fuse bias
#pragma unroll
  for (int fn = 0; fn < 4; ++fn) {
    int o = nt * 128 + wc * 64 + fn * 16 + lm;
    float bv = bias[o];
#pragma unroll
    for (int fm = 0; fm < 4; ++fm) {
      int m = m0 + wr * 64 + fm * 16 + g * 4;
      int ni = m >> 12, hh = (m >> 6) & 63, ww = m & 63;
      f32x4 v = acc[fm][fn];
      v[0] += bv; v[1] += bv; v[2] += bv; v[3] += bv;
      *(f32x4*)(out + (size_t)((ni * COUT + o) * HH + hh) * WW + ww) = v;
    }
  }
}

// ---------------- launcher ----------------
extern "C" void kernel_launch(void* const* d_in, const int* in_sizes, int n_in,
                              void* d_out, int out_size, void* d_ws, size_t ws_size,
                              hipStream_t stream) {
  const float* x = (const float*)d_in[0];
  const float* weight = (const float*)d_in[1];
  const float* bias = (const float*)d_in[2];
  const float* P = (const float*)d_in[3];
  float* out = (float*)d_out;

  const size_t xp_elems = (size_t)NIMG * HP * WP * CIN;
  ushort* xp = (ushort*)d_ws;
  ushort* kb2 = (ushort*)((char*)d_ws + xp_elems * 2);

  hipLaunchKernelGGL(pad_convert, dim3(NIMG * HP), dim3(256), 0, stream, x, xp);
  hipLaunchKernelGGL(build_kb, dim3((COUT * KW_ * CIN + 255) / 256), dim3(256), 0, stream,
                     weight, P, kb2);
  hipLaunchKernelGGL(dcls_gemm, dim3(1024), dim3(256), 0, stream, xp, kb2, bias, out);
}

// Round 10
// 184.801 us; speedup vs baseline: 1.1968x; 1.1968x over previous
//
#include <hip/hip_runtime.h>
#include <hip/hip_bf16.h>

// ---------------- problem constants ----------------
#define NIMG 16
#define CIN 128
#define COUT 256
#define HH 64
#define WW 64
#define KHE 7
#define KW_ 3
#define HP (HH + 6)   // 70
#define WP (WW + 2)   // 66
#define KDIM (CIN * KHE * KW_)  // 2688
#define NKT 42                  // K-tiles of 64

typedef __attribute__((ext_vector_type(8))) short short8;
typedef __attribute__((ext_vector_type(4))) float f32x4;

#define AS1(p) ((const __attribute__((address_space(1))) void*)(p))
#define AS3(p) ((__attribute__((address_space(3))) void*)(p))

// ---------------- kernel 1: pad + NCHW->NHWC transpose + f32->bf16 ----------------
__global__ void __launch_bounds__(256) pad_convert(const float* __restrict__ x,
                                                   ushort* __restrict__ xp) {
  const int bid = blockIdx.x;          // 16*70
  const int n = bid / HP, hp = bid % HP;
  const int h = hp - 3;
  ushort* dst = xp + (size_t)(n * HP + hp) * (WP * CIN);
  const int tid = threadIdx.x;

  if (h < 0 || h >= HH) {
    uint4* p = (uint4*)dst;
    uint4 z; z.x = z.y = z.z = z.w = 0u;
    for (int idx = tid; idx < (WP * CIN * 2) / 16; idx += 256) p[idx] = z;
    return;
  }

  __shared__ ushort t[CIN][WW + 1];
  for (int it = 0; it < (CIN * WW) / 256; ++it) {
    int flat = it * 256 + tid;
    int i = flat >> 6, w = flat & 63;
    float v = x[(((size_t)n * CIN + i) * HH + h) * WW + w];
    __hip_bfloat16 b = __float2bfloat16(v);
    t[i][w] = *(ushort*)&b;
  }
  __syncthreads();
  for (int it = 0; it < (WP * CIN) / 256; ++it) {
    int flat = it * 256 + tid;
    int wp = flat >> 7, i = flat & 127;
    int w = wp - 1;
    ushort v = (w < 0 || w >= WW) ? (ushort)0 : t[i][w];
    dst[flat] = v;
  }
}

// ---------------- kernel 2: build dense bf16 kernel in MFMA-fragment order ----------------
// kb2[kslice][o][32] where kslice = (kh_eff*3+kw)*4 + (i>>5), within-slice = i&31.
__global__ void __launch_bounds__(256) build_kb(const float* __restrict__ weight,
                                                const float* __restrict__ P,
                                                ushort* __restrict__ kb2) {
  int idx = blockIdx.x * 256 + threadIdx.x;
  if (idx >= COUT * KW_ * CIN) return;
  int i = idx & 127;
  int kw = (idx >> 7) % 3;
  int o = idx / (KW_ * CIN);
  int base = (o * CIN + i) * 9 + kw;

  float a[KHE] = {0.f, 0.f, 0.f, 0.f, 0.f, 0.f, 0.f};
#pragma unroll
  for (int kh = 0; kh < 3; ++kh) {
    float wv = weight[base + kh * 3];
    float p = P[base + kh * 3];
    p = fminf(2.f, fmaxf(-2.f, p));
    float pos = (float)(kh + 2) + p;
    float fl = floorf(pos);
    float fr = pos - fl;
    int r0 = (int)fl;
    float c0 = wv * (1.f - fr);
    float c1 = wv * fr;
#pragma unroll
    for (int r = 0; r < KHE; ++r) {
      a[r] += ((r0 == r) ? c0 : 0.f) + ((r0 + 1 == r) ? c1 : 0.f);
    }
  }
#pragma unroll
  for (int r = 0; r < KHE; ++r) {
    __hip_bfloat16 b = __float2bfloat16(a[r]);
    int kslice = (r * 3 + kw) * 4 + (i >> 5);
    kb2[(size_t)kslice * 8192 + o * 32 + (i & 31)] = *(ushort*)&b;
  }
}

// ---------------- kernel 3: implicit-GEMM conv, 128x128 tile, 4 waves, 3 blocks/CU ----------------
// K-tile order kh-FASTEST: kt -> kh=kt%7, kw=(kt/7)%3, ic=kt/21.
// Consecutive tiles re-read nearly the same xp rows -> L2-resident reuse even
// at 3 resident blocks/CU (R9's kh-slowest order thrashed L2: FETCH 349 MB).
__global__ void __launch_bounds__(256, 3) dcls_gemm(const ushort* __restrict__ xp,
                                                    const ushort* __restrict__ kb2,
                                                    const float* __restrict__ bias,
                                                    float* __restrict__ out) {
  __shared__ __align__(16) ushort As[3][128 * 64];   // 48 KiB

  const int tid = threadIdx.x;
  const int lane = tid & 63;
  const int wv = tid >> 6;       // 0..3
  const int wr = wv >> 1;        // 0..1 along M
  const int wc = wv & 1;         // 0..1 along N
  const int g = lane >> 4;
  const int lm = lane & 15;

  // XCD-aware swizzle: each XCD gets a contiguous logical chunk (128 blocks).
  const int bid = blockIdx.x;
  const int lid = (bid & 7) * 128 + (bid >> 3);
  const int mt = lid & 511;
  const int nt = lid >> 9;
  const int m0 = mt << 7;

  // A staging: 256 threads x 16B = 4KB per instr = 32 rows; source pre-swizzled (rule #21)
  const int swz = ((tid & 7) ^ ((tid >> 3) & 7)) * 8;

  const ushort* pA[4];
#pragma unroll
  for (int j = 0; j < 4; ++j) {
    int r = j * 32 + (tid >> 3);
    int m = m0 + r;
    int ni = m >> 12, hh = (m >> 6) & 63, ww = m & 63;
    pA[j] = xp + (size_t)((ni * HP + hh) * WP + ww) * CIN + swz;
  }

  // B fragment base: ((kslice*256 + o)*32 + g*8), o = nt*128 + wc*64 + nf*16 + lm
  const ushort* kbB = kb2 + (size_t)nt * 4096 + (size_t)wc * 2048 + lm * 32 + g * 8;

  // kh-fastest decode
#define KDEC(kt, kh_, kw_, ic_) \
    int kh_ = (kt) % 7; int kw_ = ((kt) / 7) % 3; int ic_ = (kt) / 21;

#define STAGEA(buf, kt) do { \
    KDEC(kt, kh_, kw_, ic_); \
    int offA_ = (kh_ * WP + kw_) * CIN + ic_ * 64; \
    _Pragma("unroll") \
    for (int j_ = 0; j_ < 4; ++j_) \
      __builtin_amdgcn_global_load_lds(AS1(pA[j_] + offA_), \
          AS3(&As[buf][(j_ * 32 + wv * 8) * 64]), 16, 0, 0); \
  } while (0)

#define LOADB(dst, kt) do { \
    KDEC(kt, kh_, kw_, ic_); \
    int ksl_ = (kh_ * 3 + kw_) * 4 + ic_ * 2; \
    _Pragma("unroll") \
    for (int n_ = 0; n_ < 4; ++n_) \
      _Pragma("unroll") \
      for (int kk_ = 0; kk_ < 2; ++kk_) \
        dst[n_][kk_] = *(const short8*)(kbB + (size_t)(ksl_ + kk_) * 8192 + n_ * 512); \
  } while (0)

  f32x4 acc[4][4] = {};
  const int swzR = (lm & 7) << 4;

  short8 bf0[4][2], bf1[4][2];
  short8 af[4];

  // one kk half: 4 ds_read_b128 -> wait -> 16 MFMA
#define HALF(Ab, bfc, kk) do { \
    _Pragma("unroll") \
    for (int m4_ = 0; m4_ < 4; ++m4_) { \
      int rowA_ = wr * 64 + m4_ * 16 + lm; \
      af[m4_] = *(const short8*)((Ab) + rowA_ * 128 + (((kk) * 64 + g * 16) ^ swzR)); \
    } \
    __builtin_amdgcn_sched_barrier(0); \
    asm volatile("s_waitcnt lgkmcnt(0)" ::: "memory"); \
    __builtin_amdgcn_sched_barrier(0); \
    __builtin_amdgcn_s_setprio(1); \
    _Pragma("unroll") \
    for (int m4_ = 0; m4_ < 4; ++m4_) \
      _Pragma("unroll") \
      for (int n_ = 0; n_ < 4; ++n_) \
        acc[m4_][n_] = __builtin_amdgcn_mfma_f32_16x16x32_bf16( \
            af[m4_], bfc[n_][kk], acc[m4_][n_], 0, 0, 0); \
    __builtin_amdgcn_s_setprio(0); \
  } while (0)

  // one K-tile: vmcnt gate + data-ready barrier; compute; reads-done barrier; stage+prefetch
#define SUBITER(kt, bfc) do { \
    __builtin_amdgcn_sched_barrier(0); \
    asm volatile("s_waitcnt vmcnt(12)" ::: "memory"); \
    __builtin_amdgcn_s_barrier(); \
    __builtin_amdgcn_sched_barrier(0); \
    const char* Ab = (const char*)&As[(kt) % 3][0]; \
    HALF(Ab, bfc, 0); \
    HALF(Ab, bfc, 1); \
    __builtin_amdgcn_sched_barrier(0); \
    __builtin_amdgcn_s_barrier(); \
    __builtin_amdgcn_sched_barrier(0); \
    int ktn_ = ((kt) + 2 < NKT) ? (kt) + 2 : 0; \
    STAGEA(((kt) + 2) % 3, ktn_); \
    LOADB(bfc, ktn_); \
  } while (0)

  // prologue: A0,B0,A1,B1 -> 24 outstanding
  STAGEA(0, 0);
  LOADB(bf0, 0);
  STAGEA(1, 1);
  LOADB(bf1, 1);

  for (int kt = 0; kt < NKT; kt += 2) {
    SUBITER(kt, bf0);
    SUBITER(kt + 1, bf1);
  }
#undef SUBITER
#undef HALF
#undef LOADB
#undef STAGEA
#undef KDEC

  // keep tail prefetches alive (vmcnt-count integrity under unroll+DCE)
#pragma unroll
  for (int n_ = 0; n_ < 4; ++n_)
#pragma unroll
    for (int kk_ = 0; kk_ < 2; ++kk_) {
      asm volatile("" :: "v"((int)bf0[n_][kk_][0]));
      asm volatile("" :: "v"((int)bf1[n_][kk_][0]));
    }

  // epilogue: C/D layout col(o)=lane&15, row(m)=(lane>>4)*4+reg; fuse bias
#pragma unroll
  for (int fn = 0; fn < 4; ++fn) {
    int o = nt * 128 + wc * 64 + fn * 16 + lm;
    float bv = bias[o];
#pragma unroll
    for (int fm = 0; fm < 4; ++fm) {
      int m = m0 + wr * 64 + fm * 16 + g * 4;
      int ni = m >> 12, hh = (m >> 6) & 63, ww = m & 63;
      f32x4 v = acc[fm][fn];
      v[0] += bv; v[1] += bv; v[2] += bv; v[3] += bv;
      *(f32x4*)(out + (size_t)((ni * COUT + o) * HH + hh) * WW + ww) = v;
    }
  }
}

// ---------------- launcher ----------------
extern "C" void kernel_launch(void* const* d_in, const int* in_sizes, int n_in,
                              void* d_out, int out_size, void* d_ws, size_t ws_size,
                              hipStream_t stream) {
  const float* x = (const float*)d_in[0];
  const float* weight = (const float*)d_in[1];
  const float* bias = (const float*)d_in[2];
  const float* P = (const float*)d_in[3];
  float* out = (float*)d_out;

  const size_t xp_elems = (size_t)NIMG * HP * WP * CIN;
  ushort* xp = (ushort*)d_ws;
  ushort* kb2 = (ushort*)((char*)d_ws + xp_elems * 2);

  hipLaunchKernelGGL(pad_convert, dim3(NIMG * HP), dim3(256), 0, stream, x, xp);
  hipLaunchKernelGGL(build_kb, dim3((COUT * KW_ * CIN + 255) / 256), dim3(256), 0, stream,
                     weight, P, kb2);
  hipLaunchKernelGGL(dcls_gemm, dim3(1024), dim3(256), 0, stream, xp, kb2, bias, out);
}

// Round 11
// 134.563 us; speedup vs baseline: 1.6436x; 1.3733x over previous
//
#include <hip/hip_runtime.h>
#include <hip/hip_bf16.h>

// ---------------- problem constants ----------------
#define NIMG 16
#define CIN 128
#define COUT 256
#define HH 64
#define WW 64
#define KHE 7
#define KW_ 3
#define HP (HH + 6)   // 70
#define WP (WW + 2)   // 66
#define KDIM (CIN * KHE * KW_)  // 2688
#define NKT 42                  // K-tiles of 64

typedef __attribute__((ext_vector_type(8))) short short8;
typedef __attribute__((ext_vector_type(4))) float f32x4;

#define AS1(p) ((const __attribute__((address_space(1))) void*)(p))
#define AS3(p) ((__attribute__((address_space(3))) void*)(p))

// ---------------- kernel 1: pad + NCHW->NHWC transpose + f32->bf16 ----------------
__global__ void __launch_bounds__(256) pad_convert(const float* __restrict__ x,
                                                   ushort* __restrict__ xp) {
  const int bid = blockIdx.x;          // 16*70
  const int n = bid / HP, hp = bid % HP;
  const int h = hp - 3;
  ushort* dst = xp + (size_t)(n * HP + hp) * (WP * CIN);
  const int tid = threadIdx.x;

  if (h < 0 || h >= HH) {
    uint4* p = (uint4*)dst;
    uint4 z; z.x = z.y = z.z = z.w = 0u;
    for (int idx = tid; idx < (WP * CIN * 2) / 16; idx += 256) p[idx] = z;
    return;
  }

  __shared__ ushort t[CIN][WW + 1];
  for (int it = 0; it < (CIN * WW) / 256; ++it) {
    int flat = it * 256 + tid;
    int i = flat >> 6, w = flat & 63;
    float v = x[(((size_t)n * CIN + i) * HH + h) * WW + w];
    __hip_bfloat16 b = __float2bfloat16(v);
    t[i][w] = *(ushort*)&b;
  }
  __syncthreads();
  for (int it = 0; it < (WP * CIN) / 256; ++it) {
    int flat = it * 256 + tid;
    int wp = flat >> 7, i = flat & 127;
    int w = wp - 1;
    ushort v = (w < 0 || w >= WW) ? (ushort)0 : t[i][w];
    dst[flat] = v;
  }
}

// ---------------- kernel 2: build dense bf16 kernel, col-granule [kt][kc][o][8] ----------------
// kt = ic*21 + kw*7 + kh  (kh-fastest K order), kc = (i&63)>>3, e = i&7.
__global__ void __launch_bounds__(256) build_kb(const float* __restrict__ weight,
                                                const float* __restrict__ P,
                                                ushort* __restrict__ kb3) {
  int idx = blockIdx.x * 256 + threadIdx.x;
  if (idx >= COUT * KW_ * CIN) return;
  int i = idx & 127;
  int kw = (idx >> 7) % 3;
  int o = idx / (KW_ * CIN);
  int base = (o * CIN + i) * 9 + kw;

  float a[KHE] = {0.f, 0.f, 0.f, 0.f, 0.f, 0.f, 0.f};
#pragma unroll
  for (int kh = 0; kh < 3; ++kh) {
    float wv = weight[base + kh * 3];
    float p = P[base + kh * 3];
    p = fminf(2.f, fmaxf(-2.f, p));
    float pos = (float)(kh + 2) + p;
    float fl = floorf(pos);
    float fr = pos - fl;
    int r0 = (int)fl;
    float c0 = wv * (1.f - fr);
    float c1 = wv * fr;
#pragma unroll
    for (int r = 0; r < KHE; ++r) {
      a[r] += ((r0 == r) ? c0 : 0.f) + ((r0 + 1 == r) ? c1 : 0.f);
    }
  }
  int ic = i >> 6, kl = i & 63, kc = kl >> 3, e = kl & 7;
#pragma unroll
  for (int r = 0; r < KHE; ++r) {
    __hip_bfloat16 b = __float2bfloat16(a[r]);
    int kt = ic * 21 + kw * 7 + r;
    kb3[((size_t)(kt * 8 + kc) * 256 + o) * 8 + e] = *(ushort*)&b;
  }
}

// ---------------- kernel 3: implicit-GEMM conv, 256x256 tile, 16 waves, A+B in LDS ----------------
// M = 65536 (256 tiles), N = 256 (1 tile), K = 42 x 64.
// 16 waves (4M x 4N), per-wave 64x64 output (acc 16 x f32x4).
// LDS col-granule [kc][row][8elems]: conflict-free frag reads, linear gload_lds dest.
// 1 barrier/tile; stage(kt+1) issued right after barrier; 4 waves/SIMD TLP.
__global__ void __launch_bounds__(1024, 4) dcls_gemm(const ushort* __restrict__ xp,
                                                     const ushort* __restrict__ kb3,
                                                     const float* __restrict__ bias,
                                                     float* __restrict__ out) {
  __shared__ __align__(16) ushort As[2][16384];   // 64 KiB: [kc 0..7][row 0..255][8]
  __shared__ __align__(16) ushort Bs[2][16384];   // 64 KiB

  const int tid = threadIdx.x;
  const int lane = tid & 63;
  const int w = tid >> 6;        // 0..15
  const int wr = w >> 2;         // 0..3 along M
  const int wc = w & 3;          // 0..3 along N
  const int g = lane >> 4;
  const int lm = lane & 15;

  // XCD-aware swizzle: 256 blocks -> 32 contiguous M-tiles per XCD (halo L2 reuse)
  const int bid = blockIdx.x;
  const int mt = (bid & 7) * 32 + (bid >> 3);
  const int m0 = mt << 8;

  // staging: chunk c = j*16 + w (c 0..31): kc = c>>2, rows (c&3)*64 + lane
  const ushort* pA[2];
  const ushort* pB[2];
#pragma unroll
  for (int j = 0; j < 2; ++j) {
    int c = j * 16 + w;
    int row = ((c & 3) << 6) + lane;
    int m = m0 + row;
    int ni = m >> 12, hh = (m >> 6) & 63, ww = m & 63;
    pA[j] = xp + (size_t)((ni * HP + hh) * WP + ww) * CIN + (c >> 2) * 8;
    pB[j] = kb3 + (size_t)(c * 64 + lane) * 8;
  }

#define STAGE(buf, kt) do { \
    int kh_ = (kt) % 7; int kw_ = ((kt) / 7) % 3; int ic_ = (kt) / 21; \
    int offA_ = (kh_ * WP + kw_) * CIN + ic_ * 64; \
    size_t offB_ = (size_t)(kt) * 16384; \
    _Pragma("unroll") \
    for (int j_ = 0; j_ < 2; ++j_) { \
      __builtin_amdgcn_global_load_lds(AS1(pA[j_] + offA_), \
          AS3(&As[buf][(j_ * 16 + w) * 512]), 16, 0, 0); \
      __builtin_amdgcn_global_load_lds(AS1(pB[j_] + offB_), \
          AS3(&Bs[buf][(j_ * 16 + w) * 512]), 16, 0, 0); \
    } \
  } while (0)

  f32x4 acc[4][4] = {};

  // frag byte offsets: (kc*256 + row)*16, kc = kk*4 + g
  const int kcOff = g << 12;                  // g*4096
  const int rowA = ((wr << 6) + lm) << 4;     // + mf*256
  const int rowB = ((wc << 6) + lm) << 4;     // + nf*256

  short8 af[4], bf[4];

#define KKSTEP(Ab, Bb, kk) do { \
    _Pragma("unroll") \
    for (int f_ = 0; f_ < 4; ++f_) { \
      af[f_] = *(const short8*)((Ab) + (kk) * 16384 + kcOff + rowA + f_ * 256); \
      bf[f_] = *(const short8*)((Bb) + (kk) * 16384 + kcOff + rowB + f_ * 256); \
    } \
    __builtin_amdgcn_sched_barrier(0); \
    asm volatile("s_waitcnt lgkmcnt(0)" ::: "memory"); \
    __builtin_amdgcn_sched_barrier(0); \
    __builtin_amdgcn_s_setprio(1); \
    _Pragma("unroll") \
    for (int mf_ = 0; mf_ < 4; ++mf_) \
      _Pragma("unroll") \
      for (int nf_ = 0; nf_ < 4; ++nf_) \
        acc[mf_][nf_] = __builtin_amdgcn_mfma_f32_16x16x32_bf16( \
            af[mf_], bf[nf_], acc[mf_][nf_], 0, 0, 0); \
    __builtin_amdgcn_s_setprio(0); \
  } while (0)

  // prologue: stage tile 0
  STAGE(0, 0);

  for (int kt = 0; kt < NKT; ++kt) {
    __builtin_amdgcn_sched_barrier(0);
    asm volatile("s_waitcnt vmcnt(0)" ::: "memory");   // stage(kt) landed (issued 1 tile ago)
    __builtin_amdgcn_s_barrier();
    __builtin_amdgcn_sched_barrier(0);
    {
      int ktn = (kt + 1 < NKT) ? kt + 1 : 0;           // wrap keeps vmcnt uniform
      STAGE((kt + 1) & 1, ktn);
    }
    const char* Ab = (const char*)&As[kt & 1][0];
    const char* Bb = (const char*)&Bs[kt & 1][0];
    KKSTEP(Ab, Bb, 0);
    KKSTEP(Ab, Bb, 1);
    // each wave's lgkmcnt(0) above guarantees its reads drained before next barrier
  }
#undef KKSTEP
#undef STAGE

  // epilogue: C/D layout col(o)=lane&15, row(m)=(lane>>4)*4+reg; fuse bias
#pragma unroll
  for (int fn = 0; fn < 4; ++fn) {
    int o = wc * 64 + fn * 16 + lm;
    float bv = bias[o];
#pragma unroll
    for (int fm = 0; fm < 4; ++fm) {
      int m = m0 + wr * 64 + fm * 16 + g * 4;
      int ni = m >> 12, hh = (m >> 6) & 63, ww = m & 63;
      f32x4 v = acc[fm][fn];
      v[0] += bv; v[1] += bv; v[2] += bv; v[3] += bv;
      *(f32x4*)(out + (size_t)((ni * COUT + o) * HH + hh) * WW + ww) = v;
    }
  }
}

// ---------------- launcher ----------------
extern "C" void kernel_launch(void* const* d_in, const int* in_sizes, int n_in,
                              void* d_out, int out_size, void* d_ws, size_t ws_size,
                              hipStream_t stream) {
  const float* x = (const float*)d_in[0];
  const float* weight = (const float*)d_in[1];
  const float* bias = (const float*)d_in[2];
  const float* P = (const float*)d_in[3];
  float* out = (float*)d_out;

  const size_t xp_elems = (size_t)NIMG * HP * WP * CIN;
  ushort* xp = (ushort*)d_ws;
  ushort* kb3 = (ushort*)((char*)d_ws + xp_elems * 2);

  hipLaunchKernelGGL(pad_convert, dim3(NIMG * HP), dim3(256), 0, stream, x, xp);
  hipLaunchKernelGGL(build_kb, dim3((COUT * KW_ * CIN + 255) / 256), dim3(256), 0, stream,
                     weight, P, kb3);
  hipLaunchKernelGGL(dcls_gemm, dim3(256), dim3(1024), 0, stream, xp, kb3, bias, out);
}